// Round 5
// baseline (238.773 us; speedup 1.0000x reference)
//
#include <hip/hip_runtime.h>
#include <math.h>

#define NH 12
#define SEQ 2048
#define DM 768
#define HD 64
#define NB 2
#define MT (NB * SEQ)          // 4096 rows
// Q pre-scale: 1/sqrt(64) * log2(e)  -> softmax via exp2
#define QSCL 0.18033688011112042591999058512524f

typedef short bf16x8 __attribute__((ext_vector_type(8)));
typedef float f32x16 __attribute__((ext_vector_type(16)));

__device__ __forceinline__ unsigned short bf16_rne(float x) {
    unsigned u = __float_as_uint(x);
    u += 0x7fffu + ((u >> 16) & 1u);
    return (unsigned short)(u >> 16);
}
__device__ __forceinline__ float bf16_tof(short h) {
    return __uint_as_float(((unsigned)(unsigned short)h) << 16);
}

__device__ __forceinline__ void gl_lds16(const void* g, void* s) {
    __builtin_amdgcn_global_load_lds(
        (const __attribute__((address_space(1))) unsigned int*)g,
        (__attribute__((address_space(3))) unsigned int*)s, 16, 0, 0);
}

__device__ __forceinline__ f32x16 mfma32(bf16x8 a, bf16x8 b, f32x16 c) {
    return __builtin_amdgcn_mfma_f32_32x32x16_bf16(a, b, c, 0, 0, 0);
}

// GEMM frag read: 64-B LDS rows (BK=32), 4 blocks of 16 B
__device__ __forceinline__ bf16x8 gfrag(const char* base, int row, int physblk) {
    return *(const bf16x8*)(base + row * 64 + physblk * 16);
}
// Attention frag read: 128-B LDS rows, 8 blocks of 16 B, key row&7
__device__ __forceinline__ bf16x8 afrag(const short* base, int row, int blk) {
    return *(const bf16x8*)(base + row * 64 + ((blk ^ (row & 7)) << 3));
}

// ---------------------------------------------------------------------------
// Merged pre-pass. Blocks [0,1536): x fp32 -> bf16 (key (m>>1)&3).
// Blocks [1536, 2688): W transpose+convert, z = (b-1536)/288.
// ---------------------------------------------------------------------------
__global__ __launch_bounds__(256)
void conv_all(const float* __restrict__ x,
              const float* __restrict__ Wq, const float* __restrict__ Wk,
              const float* __restrict__ Wv, const float* __restrict__ Wo,
              short* __restrict__ xg, short* __restrict__ wdst)
{
    int b = blockIdx.x;
    if (b < 1536) {
        const int idx = b * 256 + threadIdx.x;   // 4096*96
        const int m = idx / 96, bk = idx % 96;
        const float* src = x + (size_t)m * DM + bk * 8;
        float4 v0 = *(const float4*)src;
        float4 v1 = *(const float4*)(src + 4);
        const float vv[8] = {v0.x, v0.y, v0.z, v0.w, v1.x, v1.y, v1.z, v1.w};
        union { short s[8]; int4 q; } hh;
#pragma unroll
        for (int j = 0; j < 8; j++) hh.s[j] = (short)bf16_rne(vv[j]);
        const int pb = (bk & ~3) | ((bk & 3) ^ ((m >> 1) & 3));
        *(int4*)(xg + (size_t)m * DM + pb * 8) = hh.q;
    } else {
        b -= 1536;
        const int z = b / 288;
        const float* __restrict__ W = (z == 0) ? Wq : (z == 1) ? Wk : (z == 2) ? Wv : Wo;
        const int idx = (b % 288) * 256 + threadIdx.x;   // 96*768
        const int n = idx % 768, bk = idx / 768;
        union { short s[8]; int4 q; } hh;
#pragma unroll
        for (int j = 0; j < 8; j++) hh.s[j] = (short)bf16_rne(W[(size_t)(bk * 8 + j) * DM + n]);
        const int pb = (bk & ~3) | ((bk & 3) ^ ((n >> 1) & 3));
        *(int4*)(wdst + (size_t)z * 589824 + (size_t)n * DM + pb * 8) = hh.q;
    }
}

// ---------------------------------------------------------------------------
// QKV GEMM, single-barrier double-buffered staging. grid (6, 32, 3).
// Writes bf16 Q (pre-scaled) / K in [b][h][s][64] (key s&7) and V^T
// [b][h][hd][2048] (key hd&7 per 64-key group).
// ---------------------------------------------------------------------------
__global__ __launch_bounds__(256)
void gemm_qkv(const short* __restrict__ xg, const short* __restrict__ wt,
              const float* __restrict__ bq, const float* __restrict__ bkv,
              const float* __restrict__ bv,
              short* __restrict__ qg, short* __restrict__ kg, short* __restrict__ vg)
{
    const int z = blockIdx.z;
    const short* __restrict__ Bw = wt + (size_t)z * 589824;
    const float* __restrict__ bias = (z == 0) ? bq : (z == 1) ? bkv : bv;

    __shared__ short As[8192], Bs[8192];   // 2 x 8KB each (double buffer)
    const int t = threadIdx.x, w = t >> 6, l = t & 63;
    const int by = blockIdx.y, bx = blockIdx.x;

    const int lr = w * 32 + (l >> 2);
    const char* pA = (const char*)xg + (size_t)(by * 128 + lr) * 1536 + (l & 3) * 16;
    const char* pB = (const char*)Bw + (size_t)(bx * 128 + lr) * 1536 + (l & 3) * 16;
    const int lo = w * 2048;

    const int mrow = (w >> 1) * 64 + (l & 31);
    const int nrow = (w & 1) * 64 + (l & 31);
    const int sel  = ((l & 31) >> 1) & 3;
    const int half = l >> 5;

    f32x16 acc[2][2];
#pragma unroll
    for (int i = 0; i < 2; i++)
#pragma unroll
        for (int j = 0; j < 2; j++)
#pragma unroll
            for (int r = 0; r < 16; r++) acc[i][j][r] = 0.f;

    // prologue: stage k-step 0 into buffer 0
#pragma unroll
    for (int i = 0; i < 2; i++) {
        gl_lds16(pA + i * 24576, (char*)As + lo + i * 1024);
        gl_lds16(pB + i * 24576, (char*)Bs + lo + i * 1024);
    }
    __syncthreads();

    for (int ki = 0; ki < 24; ki++) {
        const int cur = ki & 1;
        if (ki < 23) {
            const size_t cb = (size_t)(ki + 1) * 64;
            char* dA = (char*)As + (cur ^ 1) * 8192 + lo;
            char* dB = (char*)Bs + (cur ^ 1) * 8192 + lo;
#pragma unroll
            for (int i = 0; i < 2; i++) {
                gl_lds16(pA + i * 24576 + cb, dA + i * 1024);
                gl_lds16(pB + i * 24576 + cb, dB + i * 1024);
            }
        }
        const char* sA = (const char*)As + cur * 8192;
        const char* sB = (const char*)Bs + cur * 8192;
#pragma unroll
        for (int s = 0; s < 2; s++) {
            const int blk = s * 2 + half;
            bf16x8 a0 = gfrag(sA, mrow,      blk ^ sel);
            bf16x8 a1 = gfrag(sA, mrow + 32, blk ^ sel);
            bf16x8 b0 = gfrag(sB, nrow,      blk ^ sel);
            bf16x8 b1 = gfrag(sB, nrow + 32, blk ^ sel);
            acc[0][0] = mfma32(a0, b0, acc[0][0]);
            acc[0][1] = mfma32(a0, b1, acc[0][1]);
            acc[1][0] = mfma32(a1, b0, acc[1][0]);
            acc[1][1] = mfma32(a1, b1, acc[1][1]);
        }
        __syncthreads();
    }

    const int mb = by * 128 + (w >> 1) * 64 + 4 * half;
    const int nb = bx * 128 + (w & 1) * 64 + (l & 31);

    if (z == 2) {
        // V transposed: pack 4 consecutive s into one 8-B store
#pragma unroll
        for (int ti = 0; ti < 2; ti++)
#pragma unroll
            for (int g = 0; g < 4; g++)
#pragma unroll
                for (int tj = 0; tj < 2; tj++) {
                    const int m0 = mb + ti * 32 + 8 * g;
                    const int bb = m0 >> 11, ss = m0 & 2047;
                    const int n = nb + tj * 32;
                    const int h = n >> 6, hd = n & 63;
                    const float bia = bias[n];
                    union { unsigned short u[4]; uint2 q; } pk;
#pragma unroll
                    for (int j = 0; j < 4; j++)
                        pk.u[j] = bf16_rne(acc[ti][tj][4 * g + j] + bia);
                    const int blk = ss >> 3;
                    const int phys = (blk & ~7) | ((blk & 7) ^ (hd & 7));
                    *(uint2*)(vg + ((size_t)(bb * NH + h) * HD + hd) * SEQ + phys * 8 + (ss & 7)) = pk.q;
                }
    } else {
        short* dst = (z == 0) ? qg : kg;
        const float scl = (z == 0) ? QSCL : 1.0f;
#pragma unroll
        for (int ti = 0; ti < 2; ti++)
#pragma unroll
            for (int tj = 0; tj < 2; tj++) {
                const int n = nb + tj * 32;
                const int h = n >> 6, hd = n & 63;
                const float bia = bias[n];
                const int blk = hd >> 3;
#pragma unroll
                for (int r = 0; r < 16; r++) {
                    const int m = mb + ti * 32 + (r & 3) + 8 * (r >> 2);
                    const int bb = m >> 11, ss = m & 2047;
                    const int phys = blk ^ (ss & 7);
                    dst[((size_t)(bb * NH + h) * SEQ + ss) * HD + phys * 8 + (hd & 7)] =
                        (short)bf16_rne((acc[ti][tj][r] + bia) * scl);
                }
            }
    }
}

// ---------------------------------------------------------------------------
// MFMA flash attention, no-max softmax, K-split (z=2), single-barrier
// double-buffered K/V pipeline. Q's LDS is reused as the second K/V buffer
// after the Q fragments are register-cached. P stored as packed b32
// (cols c, c+32 interleaved), deinterleaved on read with v_perm_b32.
// grid (16, 24, 2), block 256. LDS 48 KB -> 3 blocks/CU.
// ---------------------------------------------------------------------------
__global__ __launch_bounds__(256)
void attn_mfma(const short* __restrict__ qg, const short* __restrict__ kg,
               const short* __restrict__ vg,
               short* __restrict__ opart, float* __restrict__ lpart)
{
    __shared__ short Qs[8192];   // Q 128x64; later buf1: K = Qs[0..4095], V = Qs[4096..]
    __shared__ short Ks[4096];   // buf0 K (64 x 64, key s&7)
    __shared__ short Vt[4096];   // buf0 V^T (64 x 64, key hd&7)
    __shared__ short Ps[8192];   // 4 waves x 32 x 64, packed interleaved

    const int t = threadIdx.x, w = t >> 6, l = t & 63;
    const int bh = blockIdx.y, q0 = blockIdx.x * 128, ks = blockIdx.z;
    const char* qp = (const char*)(qg + (size_t)bh * SEQ * HD);
    const char* kp = (const char*)(kg + (size_t)bh * SEQ * HD);
    const char* vp = (const char*)(vg + (size_t)bh * HD * SEQ);
    const int kbase = ks * 1024;

    // prologue: stage Q and K/V tile 0
#pragma unroll
    for (int i = 0; i < 4; i++)
        gl_lds16(qp + (size_t)(q0 + w * 32 + i * 8) * 128 + l * 16,
                 (char*)Qs + (w * 32 + i * 8) * 128);
#pragma unroll
    for (int i = 0; i < 2; i++) {
        gl_lds16(kp + (size_t)(kbase + w * 16 + i * 8) * 128 + l * 16,
                 (char*)Ks + (w * 16 + i * 8) * 128);
        gl_lds16(vp + (size_t)(w * 16 + i * 8 + (l >> 3)) * 4096 + kbase * 2 + (l & 7) * 16,
                 (char*)Vt + (w * 16 + i * 8) * 128);
    }
    __syncthreads();

    const int half = l >> 5;
    bf16x8 qf[4];
#pragma unroll
    for (int s = 0; s < 4; s++)
        qf[s] = afrag(Qs, w * 32 + (l & 31), half + s * 2);
    __syncthreads();   // all waves done with Qs; it may now be overwritten

    f32x16 oacc[2], lacc;
#pragma unroll
    for (int nt = 0; nt < 2; nt++)
#pragma unroll
        for (int r = 0; r < 16; r++) oacc[nt][r] = 0.f;
#pragma unroll
    for (int r = 0; r < 16; r++) lacc[r] = 0.f;

    bf16x8 onesf;
#pragma unroll
    for (int j = 0; j < 8; j++) onesf[j] = (short)0x3F80;   // bf16 1.0

    short* psw = Ps + w * 2048;
    const int q = l & 31, key = q & 7;

    for (int kti = 0; kti < 16; kti++) {
        const int cur = kti & 1;
        // prefetch next tile into the other buffer (drained by end barrier)
        if (kti < 15) {
            const int kb0 = kbase + (kti + 1) * 64;
            char* kd = cur ? (char*)Ks : (char*)Qs;
            char* vd = cur ? (char*)Vt : (char*)(Qs + 4096);
#pragma unroll
            for (int i = 0; i < 2; i++) {
                gl_lds16(kp + (size_t)(kb0 + w * 16 + i * 8) * 128 + l * 16,
                         kd + (w * 16 + i * 8) * 128);
                gl_lds16(vp + (size_t)(w * 16 + i * 8 + (l >> 3)) * 4096 + kb0 * 2 + (l & 7) * 16,
                         vd + (w * 16 + i * 8) * 128);
            }
        }
        const short* kc = cur ? Qs : Ks;
        const short* vc = cur ? Qs + 4096 : Vt;

        // S = Q K^T  (q pre-scaled by 0.125*log2e)
        f32x16 sacc[2];
#pragma unroll
        for (int nt = 0; nt < 2; nt++)
#pragma unroll
            for (int r = 0; r < 16; r++) sacc[nt][r] = 0.f;
#pragma unroll
        for (int s = 0; s < 4; s++)
#pragma unroll
            for (int nt = 0; nt < 2; nt++) {
                bf16x8 kf = afrag(kc, nt * 32 + q, half + s * 2);
                sacc[nt] = mfma32(qf[s], kf, sacc[nt]);
            }

        // P = exp2(S): pack cols (c, c+32) into one b32 (phys idx 2c, 2c+1)
#pragma unroll
        for (int r = 0; r < 16; r++) {
            const int row = (r & 3) + 8 * (r >> 2) + 4 * half;
            const float p0 = exp2f(sacc[0][r]);
            const float p1 = exp2f(sacc[1][r]);
            const unsigned pk = ((unsigned)bf16_rne(p1) << 16) | (unsigned)bf16_rne(p0);
            *(unsigned*)(psw + row * 64 + (((q >> 2) ^ (row & 7)) << 3) + ((2 * q) & 7)) = pk;
        }

        // O += P V ; l += P @ ones  (deinterleave: even->s=a, odd->s=a+2)
#pragma unroll
        for (int a = 0; a < 2; a++) {
            union { uint4 u; bf16x8 v; } w0, w1, pe, po;
            w0.v = *(const bf16x8*)(psw + q * 64 + (((4 * a + 2 * half)     ^ key) << 3));
            w1.v = *(const bf16x8*)(psw + q * 64 + (((4 * a + 2 * half + 1) ^ key) << 3));
            pe.u.x = __builtin_amdgcn_perm(w0.u.y, w0.u.x, 0x05040100u);
            pe.u.y = __builtin_amdgcn_perm(w0.u.w, w0.u.z, 0x05040100u);
            pe.u.z = __builtin_amdgcn_perm(w1.u.y, w1.u.x, 0x05040100u);
            pe.u.w = __builtin_amdgcn_perm(w1.u.w, w1.u.z, 0x05040100u);
            po.u.x = __builtin_amdgcn_perm(w0.u.y, w0.u.x, 0x07060302u);
            po.u.y = __builtin_amdgcn_perm(w0.u.w, w0.u.z, 0x07060302u);
            po.u.z = __builtin_amdgcn_perm(w1.u.y, w1.u.x, 0x07060302u);
            po.u.w = __builtin_amdgcn_perm(w1.u.w, w1.u.z, 0x07060302u);
            lacc = mfma32(pe.v, onesf, lacc);
            lacc = mfma32(po.v, onesf, lacc);
#pragma unroll
            for (int nt = 0; nt < 2; nt++) {
                bf16x8 vfa = afrag(vc, nt * 32 + q, half + a * 2);
                bf16x8 vfb = afrag(vc, nt * 32 + q, half + (a + 2) * 2);
                oacc[nt] = mfma32(pe.v, vfa, oacc[nt]);
                oacc[nt] = mfma32(po.v, vfb, oacc[nt]);
            }
        }
        __syncthreads();   // drains prefetch DMA; all waves done with cur buffer
    }

    // epilogue: unnormalized partials
    const size_t base = (size_t)(ks * 24 + bh) * SEQ;
#pragma unroll
    for (int r = 0; r < 16; r++) {
        const int row = q0 + w * 32 + (r & 3) + 8 * (r >> 2) + 4 * half;
#pragma unroll
        for (int nt = 0; nt < 2; nt++)
            opart[(base + row) * 64 + nt * 32 + q] = (short)bf16_rne(oacc[nt][r]);
        if (q == 0) lpart[base + row] = lacc[r];
    }
}

// ---------------------------------------------------------------------------
// Output projection with fused K-split combine: A = (O0+O1)/(l0+l1) staged
// through registers -> LDS (2-deep pipeline); B via DMA double buffer.
// out = A @ Wo + bo, fp32. grid (6, 32), block 256.
// ---------------------------------------------------------------------------
__global__ __launch_bounds__(256)
void gemm_out(const short* __restrict__ opart, const float* __restrict__ lpart,
              const short* __restrict__ wt3, const float* __restrict__ bias,
              float* __restrict__ out)
{
    __shared__ short As[8192], Bs[8192];   // 2 buffers each
    const int t = threadIdx.x, w = t >> 6, l = t & 63;
    const int by = blockIdx.y, bx = blockIdx.x;

    // A-combine mapping: thread = (row lr, column half ch)
    const int lr = t >> 1, ch = t & 1;
    const int m = by * 128 + lr;
    const int bb = m >> 11, s = m & 2047;
    const int key2 = (lr >> 1) & 3;

    // B DMA mapping
    const int blr = w * 32 + (l >> 2);
    const char* pB = (const char*)wt3 + (size_t)(bx * 128 + blr) * 1536 + (l & 3) * 16;
    const int lo = w * 2048;

    uint4 ra[2][4];
    float rl[2][2];

    auto aload = [&](int ki, int slot) {
        const int h = ki >> 1;
        const int hd0 = (ki & 1) * 32 + ch * 16;
        const int bhh = bb * NH + h;
        const short* p0 = opart + ((size_t)bhh * SEQ + s) * 64 + hd0;
        const short* p1 = p0 + (size_t)24 * SEQ * 64;
        ra[slot][0] = *(const uint4*)p0;
        ra[slot][1] = *(const uint4*)(p0 + 8);
        ra[slot][2] = *(const uint4*)p1;
        ra[slot][3] = *(const uint4*)(p1 + 8);
        rl[slot][0] = lpart[(size_t)bhh * SEQ + s];
        rl[slot][1] = lpart[(size_t)(24 + bhh) * SEQ + s];
    };
    auto acommit = [&](int slot, int buf) {
        const float inv = 1.0f / (rl[slot][0] + rl[slot][1]);
        union { uint4 u; short sh[8]; } x0, x1, y0, y1, o0, o1;
        x0.u = ra[slot][0]; x1.u = ra[slot][1];
        y0.u = ra[slot][2]; y1.u = ra[slot][3];
#pragma unroll
        for (int j = 0; j < 8; j++) {
            o0.sh[j] = (short)bf16_rne((bf16_tof(x0.sh[j]) + bf16_tof(y0.sh[j])) * inv);
            o1.sh[j] = (short)bf16_rne((bf16_tof(x1.sh[j]) + bf16_tof(y1.sh[j])) * inv);
        }
        short* dst = As + buf * 4096 + lr * 32;
        *(uint4*)(dst + (((ch * 2)     ^ key2) << 3)) = o0.u;
        *(uint4*)(dst + (((ch * 2 + 1) ^ key2) << 3)) = o1.u;
    };
    auto bissue = [&](int ki, int buf) {
#pragma unroll
        for (int i = 0; i < 2; i++)
            gl_lds16(pB + i * 24576 + (size_t)ki * 64, (char*)Bs + buf * 8192 + lo + i * 1024);
    };

    const int mrow = (w >> 1) * 64 + (l & 31);
    const int nrow = (w & 1) * 64 + (l & 31);
    const int sel  = ((l & 31) >> 1) & 3;
    const int half = l >> 5;

    f32x16 acc[2][2];
#pragma unroll
    for (int i = 0; i < 2; i++)
#pragma unroll
        for (int j = 0; j < 2; j++)
#pragma unroll
            for (int r = 0; r < 16; r++) acc[i][j][r] = 0.f;

    // prologue
    bissue(0, 0);
    aload(0, 0);
    acommit(0, 0);
    aload(1, 1);
    __syncthreads();

    for (int ki = 0; ki < 24; ki++) {
        const int cur = ki & 1;
        if (ki < 23) {
            bissue(ki + 1, cur ^ 1);
            acommit((ki + 1) & 1, cur ^ 1);
        }
        if (ki < 22) aload(ki + 2, ki & 1);
        const char* sA = (const char*)(As + cur * 4096);
        const char* sB = (const char*)Bs + cur * 8192;
#pragma unroll
        for (int ss = 0; ss < 2; ss++) {
            const int blk = ss * 2 + half;
            bf16x8 a0 = gfrag(sA, mrow,      blk ^ sel);
            bf16x8 a1 = gfrag(sA, mrow + 32, blk ^ sel);
            bf16x8 b0 = gfrag(sB, nrow,      blk ^ sel);
            bf16x8 b1 = gfrag(sB, nrow + 32, blk ^ sel);
            acc[0][0] = mfma32(a0, b0, acc[0][0]);
            acc[0][1] = mfma32(a0, b1, acc[0][1]);
            acc[1][0] = mfma32(a1, b0, acc[1][0]);
            acc[1][1] = mfma32(a1, b1, acc[1][1]);
        }
        __syncthreads();
    }

    const int mb = by * 128 + (w >> 1) * 64 + 4 * half;
    const int nb = bx * 128 + (w & 1) * 64 + (l & 31);
#pragma unroll
    for (int ti = 0; ti < 2; ti++)
#pragma unroll
        for (int tj = 0; tj < 2; tj++) {
            const int n = nb + tj * 32;
            const float bia = bias[n];
#pragma unroll
            for (int r = 0; r < 16; r++) {
                const int mm = mb + ti * 32 + (r & 3) + 8 * (r >> 2);
                out[(size_t)mm * DM + n] = acc[ti][tj][r] + bia;
            }
        }
}

// ---------------------------------------------------------------------------
extern "C" void kernel_launch(void* const* d_in, const int* in_sizes, int n_in,
                              void* d_out, int out_size, void* d_ws, size_t ws_size,
                              hipStream_t stream)
{
    const float* x  = (const float*)d_in[0];
    const float* Wq = (const float*)d_in[1];
    const float* bq = (const float*)d_in[2];
    const float* Wk = (const float*)d_in[3];
    const float* bk = (const float*)d_in[4];
    const float* Wv = (const float*)d_in[5];
    const float* bv = (const float*)d_in[6];
    const float* Wo = (const float*)d_in[7];
    const float* bo = (const float*)d_in[8];
    float* out = (float*)d_out;

    const size_t BUF = (size_t)MT * DM;   // 3,145,728 elements
    short* xg = (short*)d_ws;
    short* qg = xg + BUF;
    short* kg = qg + BUF;
    short* vg = kg + BUF;
    short* wt = vg + BUF;                       // 4 * 589824
    short* opart = wt + (size_t)4 * 589824;     // 2*24*2048*64 shorts
    float* lpart = (float*)(opart + (size_t)2 * 24 * SEQ * HD);  // 2*24*2048 floats

    conv_all<<<2688, 256, 0, stream>>>(x, Wq, Wk, Wv, Wo, xg, wt);
    gemm_qkv<<<dim3(6, 32, 3), 256, 0, stream>>>(xg, wt, bq, bk, bv, qg, kg, vg);
    attn_mfma<<<dim3(16, 24, 2), 256, 0, stream>>>(qg, kg, vg, opart, lpart);
    gemm_out<<<dim3(6, 32), 256, 0, stream>>>(opart, lpart, wt + (size_t)3 * 589824, bo, out);
}

// Round 6
// 204.145 us; speedup vs baseline: 1.1696x; 1.1696x over previous
//
#include <hip/hip_runtime.h>
#include <math.h>

#define NH 12
#define SEQ 2048
#define DM 768
#define HD 64
#define NB 2
#define MT (NB * SEQ)          // 4096 rows
// Q pre-scale: 1/sqrt(64) * log2(e)  -> softmax via exp2
#define QSCL 0.18033688011112042591999058512524f

typedef short bf16x8 __attribute__((ext_vector_type(8)));
typedef float f32x16 __attribute__((ext_vector_type(16)));

__device__ __forceinline__ unsigned short bf16_rne(float x) {
    unsigned u = __float_as_uint(x);
    u += 0x7fffu + ((u >> 16) & 1u);
    return (unsigned short)(u >> 16);
}
__device__ __forceinline__ float bf16_tof(short h) {
    return __uint_as_float(((unsigned)(unsigned short)h) << 16);
}

__device__ __forceinline__ void gl_lds16(const void* g, void* s) {
    __builtin_amdgcn_global_load_lds(
        (const __attribute__((address_space(1))) unsigned int*)g,
        (__attribute__((address_space(3))) unsigned int*)s, 16, 0, 0);
}

__device__ __forceinline__ f32x16 mfma32(bf16x8 a, bf16x8 b, f32x16 c) {
    return __builtin_amdgcn_mfma_f32_32x32x16_bf16(a, b, c, 0, 0, 0);
}

// GEMM frag read: 64-B LDS rows (BK=32), 4 blocks of 16 B
__device__ __forceinline__ bf16x8 gfrag(const char* base, int row, int physblk) {
    return *(const bf16x8*)(base + row * 64 + physblk * 16);
}
// Attention frag read: 128-B LDS rows, 8 blocks of 16 B, key row&7
__device__ __forceinline__ bf16x8 afrag(const short* base, int row, int blk) {
    return *(const bf16x8*)(base + row * 64 + ((blk ^ (row & 7)) << 3));
}

// ---------------------------------------------------------------------------
// Merged pre-pass. Blocks [0,1536): x fp32 -> bf16 (key (m>>1)&3).
// Blocks [1536, 2688): W transpose+convert, z = (b-1536)/288.
// ---------------------------------------------------------------------------
__global__ __launch_bounds__(256)
void conv_all(const float* __restrict__ x,
              const float* __restrict__ Wq, const float* __restrict__ Wk,
              const float* __restrict__ Wv, const float* __restrict__ Wo,
              short* __restrict__ xg, short* __restrict__ wdst)
{
    int b = blockIdx.x;
    if (b < 1536) {
        const int idx = b * 256 + threadIdx.x;   // 4096*96
        const int m = idx / 96, bk = idx % 96;
        const float* src = x + (size_t)m * DM + bk * 8;
        float4 v0 = *(const float4*)src;
        float4 v1 = *(const float4*)(src + 4);
        const float vv[8] = {v0.x, v0.y, v0.z, v0.w, v1.x, v1.y, v1.z, v1.w};
        union { short s[8]; int4 q; } hh;
#pragma unroll
        for (int j = 0; j < 8; j++) hh.s[j] = (short)bf16_rne(vv[j]);
        const int pb = (bk & ~3) | ((bk & 3) ^ ((m >> 1) & 3));
        *(int4*)(xg + (size_t)m * DM + pb * 8) = hh.q;
    } else {
        b -= 1536;
        const int z = b / 288;
        const float* __restrict__ W = (z == 0) ? Wq : (z == 1) ? Wk : (z == 2) ? Wv : Wo;
        const int idx = (b % 288) * 256 + threadIdx.x;   // 96*768
        const int n = idx % 768, bk = idx / 768;
        union { short s[8]; int4 q; } hh;
#pragma unroll
        for (int j = 0; j < 8; j++) hh.s[j] = (short)bf16_rne(W[(size_t)(bk * 8 + j) * DM + n]);
        const int pb = (bk & ~3) | ((bk & 3) ^ ((n >> 1) & 3));
        *(int4*)(wdst + (size_t)z * 589824 + (size_t)n * DM + pb * 8) = hh.q;
    }
}

// ---------------------------------------------------------------------------
// QKV GEMM (R4 2-barrier structure). Writes bf16 Q (pre-scaled) / K in
// [b][h][s][64] (key s&7) and V^T [b][h][hd][2048] with pi-interleaved k
// within each 64-group: dword D=c holds keys (c, c+32); 16B blocks
// XOR-swizzled by hd&7. grid (6, 32, 3), block 256.
// ---------------------------------------------------------------------------
__global__ __launch_bounds__(256)
void gemm_qkv(const short* __restrict__ xg, const short* __restrict__ wt,
              const float* __restrict__ bq, const float* __restrict__ bkv,
              const float* __restrict__ bv,
              short* __restrict__ qg, short* __restrict__ kg, short* __restrict__ vg)
{
    const int z = blockIdx.z;
    const short* __restrict__ Bw = wt + (size_t)z * 589824;
    const float* __restrict__ bias = (z == 0) ? bq : (z == 1) ? bkv : bv;

    __shared__ short As[4096], Bs[4096];   // 8 KB each
    const int t = threadIdx.x, w = t >> 6, l = t & 63;
    const int by = blockIdx.y, bx = blockIdx.x;

    const int lr = w * 32 + (l >> 2);
    const char* pA = (const char*)xg + (size_t)(by * 128 + lr) * 1536 + (l & 3) * 16;
    const char* pB = (const char*)Bw + (size_t)(bx * 128 + lr) * 1536 + (l & 3) * 16;
    char* sA = (char*)As;
    char* sB = (char*)Bs;
    const int lo = w * 2048;

    const int mrow = (w >> 1) * 64 + (l & 31);
    const int nrow = (w & 1) * 64 + (l & 31);
    const int sel  = ((l & 31) >> 1) & 3;
    const int half = l >> 5;

    f32x16 acc[2][2];
#pragma unroll
    for (int i = 0; i < 2; i++)
#pragma unroll
        for (int j = 0; j < 2; j++)
#pragma unroll
            for (int r = 0; r < 16; r++) acc[i][j][r] = 0.f;

    for (int k0 = 0; k0 < DM; k0 += 32) {
        const size_t cb = (size_t)k0 * 2;
        __syncthreads();
#pragma unroll
        for (int i = 0; i < 2; i++) {
            gl_lds16(pA + i * 24576 + cb, sA + lo + i * 1024);
            gl_lds16(pB + i * 24576 + cb, sB + lo + i * 1024);
        }
        __syncthreads();
#pragma unroll
        for (int s = 0; s < 2; s++) {
            const int blk = s * 2 + half;
            bf16x8 a0 = gfrag(sA, mrow,      blk ^ sel);
            bf16x8 a1 = gfrag(sA, mrow + 32, blk ^ sel);
            bf16x8 b0 = gfrag(sB, nrow,      blk ^ sel);
            bf16x8 b1 = gfrag(sB, nrow + 32, blk ^ sel);
            acc[0][0] = mfma32(a0, b0, acc[0][0]);
            acc[0][1] = mfma32(a0, b1, acc[0][1]);
            acc[1][0] = mfma32(a1, b0, acc[1][0]);
            acc[1][1] = mfma32(a1, b1, acc[1][1]);
        }
    }

    const int mb = by * 128 + (w >> 1) * 64 + 4 * half;
    const int nb = bx * 128 + (w & 1) * 64 + (l & 31);

    if (z == 2) {
        // V^T, pi-interleaved: (ti=0, ti=1) pair for the same r packs keys
        // (c, c+32) into one b32 at logical dword D = 4*half + rtilde.
        const int hb  = mb >> 11;                     // batch (uniform for pair)
        const int g64 = (mb & 2047) - 4 * half;       // 64-aligned group base
#pragma unroll
        for (int tj = 0; tj < 2; tj++) {
            const int n = nb + tj * 32;
            const int h = n >> 6, hd = n & 63;
            const float bia = bias[n];
            unsigned* dstrow = (unsigned*)(vg + ((size_t)(hb * NH + h) * HD + hd) * SEQ + g64);
#pragma unroll
            for (int r = 0; r < 16; r++) {
                const int rt = (r & 3) + 8 * (r >> 2);
                const int D  = 4 * half + rt;                        // 0..31
                const int Dp = (((D >> 2) ^ (hd & 7)) << 2) | (D & 3);
                const unsigned pk =
                    ((unsigned)bf16_rne(acc[1][tj][r] + bia) << 16) |
                     (unsigned)bf16_rne(acc[0][tj][r] + bia);
                dstrow[Dp] = pk;
            }
        }
    } else {
        short* dst = (z == 0) ? qg : kg;
        const float scl = (z == 0) ? QSCL : 1.0f;
#pragma unroll
        for (int ti = 0; ti < 2; ti++)
#pragma unroll
            for (int tj = 0; tj < 2; tj++) {
                const int n = nb + tj * 32;
                const int h = n >> 6, hd = n & 63;
                const float bia = bias[n];
                const int blk = hd >> 3;
#pragma unroll
                for (int r = 0; r < 16; r++) {
                    const int m = mb + ti * 32 + (r & 3) + 8 * (r >> 2);
                    const int bb = m >> 11, ss = m & 2047;
                    const int phys = blk ^ (ss & 7);
                    dst[((size_t)(bb * NH + h) * SEQ + ss) * HD + phys * 8 + (hd & 7)] =
                        (short)bf16_rne((acc[ti][tj][r] + bia) * scl);
                }
            }
    }
}

// ---------------------------------------------------------------------------
// MFMA flash attention, no-max softmax, K-split (z=2), single-barrier
// double-buffered K/V (Q's LDS reused as buffer 1). P packed by TRUNCATION
// (one v_perm per score pair) into the pi-interleaved layout that V's
// global layout already matches -> zero deinterleave, zero RNE in P path.
// grid (16, 24, 2), block 256. LDS 48 KB -> 3 blocks/CU.
// ---------------------------------------------------------------------------
__global__ __launch_bounds__(256)
void attn_mfma(const short* __restrict__ qg, const short* __restrict__ kg,
               const short* __restrict__ vg,
               short* __restrict__ opart, float* __restrict__ lpart)
{
    __shared__ short Qs[8192];   // Q 128x64; later buf1: K = Qs[0..4095], V = Qs[4096..]
    __shared__ short Ks[4096];   // buf0 K (64 x 64, key s&7)
    __shared__ short Vt[4096];   // buf0 V^T (64 x 64, pi-k, key hd&7)
    __shared__ short Ps[8192];   // 4 waves x 32 x 64, pi-k, key row&7

    const int t = threadIdx.x, w = t >> 6, l = t & 63;
    const int bh = blockIdx.y, q0 = blockIdx.x * 128, ks = blockIdx.z;
    const char* qp = (const char*)(qg + (size_t)bh * SEQ * HD);
    const char* kp = (const char*)(kg + (size_t)bh * SEQ * HD);
    const char* vp = (const char*)(vg + (size_t)bh * HD * SEQ);
    const int kbase = ks * 1024;

    // prologue: stage Q and K/V tile 0
#pragma unroll
    for (int i = 0; i < 4; i++)
        gl_lds16(qp + (size_t)(q0 + w * 32 + i * 8) * 128 + l * 16,
                 (char*)Qs + (w * 32 + i * 8) * 128);
#pragma unroll
    for (int i = 0; i < 2; i++) {
        gl_lds16(kp + (size_t)(kbase + w * 16 + i * 8) * 128 + l * 16,
                 (char*)Ks + (w * 16 + i * 8) * 128);
        gl_lds16(vp + (size_t)(w * 16 + i * 8 + (l >> 3)) * 4096 + kbase * 2 + (l & 7) * 16,
                 (char*)Vt + (w * 16 + i * 8) * 128);
    }
    __syncthreads();

    const int half = l >> 5;
    const int q = l & 31;
    bf16x8 qf[4];
#pragma unroll
    for (int s = 0; s < 4; s++)
        qf[s] = afrag(Qs, w * 32 + q, half + s * 2);
    __syncthreads();   // all waves done with Qs; it may now be overwritten

    f32x16 oacc[2], lacc;
#pragma unroll
    for (int nt = 0; nt < 2; nt++)
#pragma unroll
        for (int r = 0; r < 16; r++) oacc[nt][r] = 0.f;
#pragma unroll
    for (int r = 0; r < 16; r++) lacc[r] = 0.f;

    bf16x8 onesf;
#pragma unroll
    for (int j = 0; j < 8; j++) onesf[j] = (short)0x3F80;   // bf16 1.0

    short* psw = Ps + w * 2048;

    for (int kti = 0; kti < 16; kti++) {
        const int cur = kti & 1;
        // prefetch next tile into the other buffer (drained by end barrier)
        if (kti < 15) {
            const int kb0 = kbase + (kti + 1) * 64;
            char* kd = cur ? (char*)Ks : (char*)Qs;
            char* vd = cur ? (char*)Vt : (char*)(Qs + 4096);
#pragma unroll
            for (int i = 0; i < 2; i++) {
                gl_lds16(kp + (size_t)(kb0 + w * 16 + i * 8) * 128 + l * 16,
                         kd + (w * 16 + i * 8) * 128);
                gl_lds16(vp + (size_t)(w * 16 + i * 8 + (l >> 3)) * 4096 + kb0 * 2 + (l & 7) * 16,
                         vd + (w * 16 + i * 8) * 128);
            }
        }
        const short* kc = cur ? Qs : Ks;
        const short* vc = cur ? Qs + 4096 : Vt;

        // S = Q K^T  (q pre-scaled by 0.125*log2e)
        f32x16 sacc[2];
#pragma unroll
        for (int nt = 0; nt < 2; nt++)
#pragma unroll
            for (int r = 0; r < 16; r++) sacc[nt][r] = 0.f;
#pragma unroll
        for (int s = 0; s < 4; s++)
#pragma unroll
            for (int nt = 0; nt < 2; nt++) {
                bf16x8 kf = afrag(kc, nt * 32 + q, half + s * 2);
                sacc[nt] = mfma32(qf[s], kf, sacc[nt]);
            }

        // P = exp2(S), truncation-packed: keys (q, q+32) -> one b32 at dword q
#pragma unroll
        for (int r = 0; r < 16; r++) {
            const int row = (r & 3) + 8 * (r >> 2) + 4 * half;
            const float p0 = exp2f(sacc[0][r]);
            const float p1 = exp2f(sacc[1][r]);
            const unsigned pk = __builtin_amdgcn_perm(
                __float_as_uint(p1), __float_as_uint(p0), 0x07060302u);
            const int Dp = (((q >> 2) ^ (row & 7)) << 2) | (q & 3);
            *(unsigned*)(psw + row * 64 + 2 * Dp) = pk;
        }

        // O += P V ; l += P @ ones  (P and V share the pi-k order directly)
#pragma unroll
        for (int s = 0; s < 4; s++) {
            bf16x8 pf = afrag(psw, q, half + s * 2);
            lacc = mfma32(pf, onesf, lacc);
#pragma unroll
            for (int nt = 0; nt < 2; nt++) {
                bf16x8 vf = afrag(vc, nt * 32 + q, half + s * 2);
                oacc[nt] = mfma32(pf, vf, oacc[nt]);
            }
        }
        __syncthreads();   // drains prefetch DMA; all waves done with cur buffer
    }

    // epilogue: unnormalized partials
    const size_t base = (size_t)(ks * 24 + bh) * SEQ;
#pragma unroll
    for (int r = 0; r < 16; r++) {
        const int row = q0 + w * 32 + (r & 3) + 8 * (r >> 2) + 4 * half;
#pragma unroll
        for (int nt = 0; nt < 2; nt++)
            opart[(base + row) * 64 + nt * 32 + q] = (short)bf16_rne(oacc[nt][r]);
        if (q == 0) lpart[base + row] = lacc[r];
    }
}

// ---------------------------------------------------------------------------
// Combine K-split partials: ag = (O0+O1)/(l0+l1), bf16, key (m>>1)&3.
// grid 1536, block 256 (thread = 8 hd of one row).
// ---------------------------------------------------------------------------
__global__ __launch_bounds__(256)
void attn_reduce(const short* __restrict__ opart, const float* __restrict__ lpart,
                 short* __restrict__ ag)
{
    const int idx = blockIdx.x * 256 + threadIdx.x;   // 49152*8
    const int cg = idx & 7, row = idx >> 3;
    const int bh = row >> 11, s = row & 2047;
    union { short s[8]; int4 q; } a, b, o;
    a.q = *(const int4*)(opart + ((size_t)bh * SEQ + s) * 64 + cg * 8);
    b.q = *(const int4*)(opart + ((size_t)(24 + bh) * SEQ + s) * 64 + cg * 8);
    const float inv = 1.0f / (lpart[(size_t)bh * SEQ + s] + lpart[(size_t)(24 + bh) * SEQ + s]);
#pragma unroll
    for (int j = 0; j < 8; j++)
        o.s[j] = (short)bf16_rne((bf16_tof(a.s[j]) + bf16_tof(b.s[j])) * inv);
    const int bb = bh / NH, h = bh % NH;
    const int m = bb * SEQ + s;
    const int blk = h * 8 + cg;
    const int phys = (blk & ~3) | ((blk & 3) ^ ((m >> 1) & 3));
    *(int4*)(ag + (size_t)m * DM + phys * 8) = o.q;
}

// ---------------------------------------------------------------------------
// Output projection (R4 2-barrier structure): out = A @ Wo + bo, fp32 out.
// grid (6, 32), block 256.
// ---------------------------------------------------------------------------
__global__ __launch_bounds__(256)
void gemm_out(const short* __restrict__ ag, const short* __restrict__ wt3,
              const float* __restrict__ bias, float* __restrict__ out)
{
    __shared__ short As[4096], Bs[4096];
    const int t = threadIdx.x, w = t >> 6, l = t & 63;
    const int by = blockIdx.y, bx = blockIdx.x;

    const int lr = w * 32 + (l >> 2);
    const char* pA = (const char*)ag  + (size_t)(by * 128 + lr) * 1536 + (l & 3) * 16;
    const char* pB = (const char*)wt3 + (size_t)(bx * 128 + lr) * 1536 + (l & 3) * 16;
    char* sA = (char*)As;
    char* sB = (char*)Bs;
    const int lo = w * 2048;

    const int mrow = (w >> 1) * 64 + (l & 31);
    const int nrow = (w & 1) * 64 + (l & 31);
    const int sel  = ((l & 31) >> 1) & 3;
    const int half = l >> 5;

    f32x16 acc[2][2];
#pragma unroll
    for (int i = 0; i < 2; i++)
#pragma unroll
        for (int j = 0; j < 2; j++)
#pragma unroll
            for (int r = 0; r < 16; r++) acc[i][j][r] = 0.f;

    for (int k0 = 0; k0 < DM; k0 += 32) {
        const size_t cb = (size_t)k0 * 2;
        __syncthreads();
#pragma unroll
        for (int i = 0; i < 2; i++) {
            gl_lds16(pA + i * 24576 + cb, sA + lo + i * 1024);
            gl_lds16(pB + i * 24576 + cb, sB + lo + i * 1024);
        }
        __syncthreads();
#pragma unroll
        for (int s = 0; s < 2; s++) {
            const int blk = s * 2 + half;
            bf16x8 a0 = gfrag(sA, mrow,      blk ^ sel);
            bf16x8 a1 = gfrag(sA, mrow + 32, blk ^ sel);
            bf16x8 b0 = gfrag(sB, nrow,      blk ^ sel);
            bf16x8 b1 = gfrag(sB, nrow + 32, blk ^ sel);
            acc[0][0] = mfma32(a0, b0, acc[0][0]);
            acc[0][1] = mfma32(a0, b1, acc[0][1]);
            acc[1][0] = mfma32(a1, b0, acc[1][0]);
            acc[1][1] = mfma32(a1, b1, acc[1][1]);
        }
    }

    const int mb = by * 128 + (w >> 1) * 64 + 4 * half;
    const int nb = bx * 128 + (w & 1) * 64 + (l & 31);
#pragma unroll
    for (int ti = 0; ti < 2; ti++)
#pragma unroll
        for (int tj = 0; tj < 2; tj++) {
            const int n = nb + tj * 32;
            const float bia = bias[n];
#pragma unroll
            for (int r = 0; r < 16; r++) {
                const int m = mb + ti * 32 + (r & 3) + 8 * (r >> 2);
                out[(size_t)m * DM + n] = acc[ti][tj][r] + bia;
            }
        }
}

// ---------------------------------------------------------------------------
extern "C" void kernel_launch(void* const* d_in, const int* in_sizes, int n_in,
                              void* d_out, int out_size, void* d_ws, size_t ws_size,
                              hipStream_t stream)
{
    const float* x  = (const float*)d_in[0];
    const float* Wq = (const float*)d_in[1];
    const float* bq = (const float*)d_in[2];
    const float* Wk = (const float*)d_in[3];
    const float* bk = (const float*)d_in[4];
    const float* Wv = (const float*)d_in[5];
    const float* bv = (const float*)d_in[6];
    const float* Wo = (const float*)d_in[7];
    const float* bo = (const float*)d_in[8];
    float* out = (float*)d_out;

    const size_t BUF = (size_t)MT * DM;   // 3,145,728 elements
    short* xg = (short*)d_ws;
    short* qg = xg + BUF;
    short* kg = qg + BUF;
    short* vg = kg + BUF;
    short* ag = vg + BUF;
    short* wt = ag + BUF;                       // 4 * 589824
    short* opart = wt + (size_t)4 * 589824;     // 2*24*2048*64 shorts
    float* lpart = (float*)(opart + (size_t)2 * 24 * SEQ * HD);  // 2*24*2048 floats

    conv_all<<<2688, 256, 0, stream>>>(x, Wq, Wk, Wv, Wo, xg, wt);
    gemm_qkv<<<dim3(6, 32, 3), 256, 0, stream>>>(xg, wt, bq, bk, bv, qg, kg, vg);
    attn_mfma<<<dim3(16, 24, 2), 256, 0, stream>>>(qg, kg, vg, opart, lpart);
    attn_reduce<<<1536, 256, 0, stream>>>(opart, lpart, ag);
    gemm_out<<<dim3(6, 32), 256, 0, stream>>>(ag, wt + (size_t)3 * 589824, bo, out);
}